// Round 7
// baseline (89.930 us; speedup 1.0000x reference)
//
#include <hip/hip_runtime.h>
#include <hip/hip_bf16.h>

// PointPillarScatter: out[1, C, NY, NX] (fp32), zero except
// out[c, y, x] = pillar_features[c, p] for pillar p at (z=0, y, x).
// C=64, NX=NY=1024, P=100000.
//   d_in[0]: pillar_features float32 [C, P]
//   d_in[1]: coords int32 [1, P, 3] (z, y, x)
//
// Inverse-map + pf transpose to [P, 64] + full-coverage gather.
// Round 7 single-variable A/B: REGULAR float4 stores instead of
// __builtin_nontemporal_store — harness fill kernels prove the regular
// write-back path sustains 6.9 TB/s; no such evidence for the nt path.

constexpr int C_CH   = 64;
constexpr int NX_G   = 1024;
constexpr int NY_G   = 1024;
constexpr int NCELLS = NX_G * NY_G;
constexpr int QUADS  = NCELLS / 4;      // 262144 = 2^18
constexpr int GROUPS = 16;              // channel groups of 4

typedef __attribute__((ext_vector_type(4))) float f32x4;

__global__ void pp_fill_map(int4* __restrict__ map) {
    int t = blockIdx.x * blockDim.x + threadIdx.x;
    map[t] = make_int4(-1, -1, -1, -1);
}

// Transpose pf [64, P] -> pfT [P, 64]; also build the cell->pillar map.
__global__ __launch_bounds__(256)
void pp_transpose_buildmap(const float* __restrict__ pf,
                           const int* __restrict__ coords,
                           float* __restrict__ pfT,
                           int* __restrict__ map, int P) {
    __shared__ float tile[64][65];   // +1 pad
    const int pbase = blockIdx.x * 64;
    const int lane  = threadIdx.x & 63;
    const int row4  = threadIdx.x >> 6;   // 0..3
    const int p     = pbase + lane;
    const bool pin  = (p < P);

    // Load 64 channels x 64 pillars, coalesced along P.
#pragma unroll
    for (int r = 0; r < 16; ++r) {
        int c = (r << 2) + row4;
        tile[c][lane] = pin ? pf[(size_t)c * P + p] : 0.0f;
    }

    // Fold in build_map: first 64 threads handle this block's pillars.
    if (threadIdx.x < 64 && pin) {
        int z = coords[3 * p + 0];
        int y = coords[3 * p + 1];
        int x = coords[3 * p + 2];
        map[z + y * NX_G + x] = p;
    }
    __syncthreads();

    // Write pfT rows: thread t -> pillar j = t>>2, channels (t&3)*16 .. +15.
    const int j  = threadIdx.x >> 2;
    const int c0 = (threadIdx.x & 3) << 4;
    if (pbase + j < P) {
        float* dst = pfT + (size_t)(pbase + j) * 64 + c0;
#pragma unroll
        for (int k = 0; k < 16; k += 4) {
            f32x4 v = { tile[c0 + k][j], tile[c0 + k + 1][j],
                        tile[c0 + k + 2][j], tile[c0 + k + 3][j] };
            *reinterpret_cast<f32x4*>(dst + k) = v;
        }
    }
}

__global__ __launch_bounds__(256)
void pp_gather(const float* __restrict__ pfT,
               const int* __restrict__ map,
               float* __restrict__ out) {
    int t = blockIdx.x * blockDim.x + threadIdx.x;  // [0, GROUPS*QUADS)
    int q = t & (QUADS - 1);    // quad-cell id -> coalesced map load + store
    int g = t >> 18;            // channel group (0..15)
    const int4 pid = reinterpret_cast<const int4*>(map)[q];
    const int c0 = g << 2;

    f32x4 a = {0,0,0,0}, b = {0,0,0,0}, c = {0,0,0,0}, d = {0,0,0,0};
    if (pid.x >= 0) a = *reinterpret_cast<const f32x4*>(pfT + ((size_t)pid.x << 6) + c0);
    if (pid.y >= 0) b = *reinterpret_cast<const f32x4*>(pfT + ((size_t)pid.y << 6) + c0);
    if (pid.z >= 0) c = *reinterpret_cast<const f32x4*>(pfT + ((size_t)pid.z << 6) + c0);
    if (pid.w >= 0) d = *reinterpret_cast<const f32x4*>(pfT + ((size_t)pid.w << 6) + c0);

    // 4x4 in-register transpose: channel c0+i gets {a[i], b[i], c[i], d[i]}.
#pragma unroll
    for (int i = 0; i < 4; ++i) {
        f32x4 v = { a[i], b[i], c[i], d[i] };
        f32x4* dst = reinterpret_cast<f32x4*>(out + (size_t)(c0 + i) * NCELLS) + q;
        *dst = v;   // regular store (A/B vs nontemporal)
    }
}

extern "C" void kernel_launch(void* const* d_in, const int* in_sizes, int n_in,
                              void* d_out, int out_size, void* d_ws, size_t ws_size,
                              hipStream_t stream) {
    const float* pf     = (const float*)d_in[0];
    const int*   coords = (const int*)d_in[1];
    float*       out    = (float*)d_out;
    int*         map    = (int*)d_ws;                       // 4 MiB
    float*       pfT    = (float*)((char*)d_ws + (size_t)NCELLS * sizeof(int)); // 25.6 MB

    const int P = in_sizes[0] / C_CH;  // 100000

    pp_fill_map<<<QUADS / 256, 256, 0, stream>>>((int4*)map);

    const int tblocks = (P + 63) / 64;  // 1563
    pp_transpose_buildmap<<<tblocks, 256, 0, stream>>>(pf, coords, pfT, map, P);

    const int threads = GROUPS * QUADS;  // 4,194,304
    pp_gather<<<threads / 256, 256, 0, stream>>>(pfT, map, out);
}

// Round 8
// 78.281 us; speedup vs baseline: 1.1488x; 1.1488x over previous
//
#include <hip/hip_runtime.h>
#include <hip/hip_bf16.h>

// PointPillarScatter: out[1, C, NY, NX] (fp32), zero except
// out[c, y, x] = pillar_features[c, p] for pillar p at (z=0, y, x).
// C=64, NX=NY=1024, P=100000.
//   d_in[0]: pillar_features float32 [C, P]
//   d_in[1]: coords int32 [1, P, 3] (z, y, x)
//
// Inverse-map + pf transpose to [P, 64] + full-coverage gather with NT
// float4 stores (round 7 proved regular stores thrash L2: 72.4 -> 89.9).
// Round 8: XCD-locality block swizzle in the gather — the 16 blocks
// covering the same quad-range (all 16 channel groups) are placed on the
// SAME XCD within a 128-block dispatch window, so the map quad-range is
// read into L2 once (reused 16x) and each pfT line gets 3/4 L2 hits.

constexpr int C_CH   = 64;
constexpr int NX_G   = 1024;
constexpr int NY_G   = 1024;
constexpr int NCELLS = NX_G * NY_G;
constexpr int QUADS  = NCELLS / 4;      // 262144 = 2^18
constexpr int GROUPS = 16;              // channel groups of 4

typedef __attribute__((ext_vector_type(4))) float f32x4;

__global__ void pp_fill_map(int4* __restrict__ map) {
    int t = blockIdx.x * blockDim.x + threadIdx.x;
    map[t] = make_int4(-1, -1, -1, -1);
}

// Transpose pf [64, P] -> pfT [P, 64]; also build the cell->pillar map.
__global__ __launch_bounds__(256)
void pp_transpose_buildmap(const float* __restrict__ pf,
                           const int* __restrict__ coords,
                           float* __restrict__ pfT,
                           int* __restrict__ map, int P) {
    __shared__ float tile[64][65];   // +1 pad
    const int pbase = blockIdx.x * 64;
    const int lane  = threadIdx.x & 63;
    const int row4  = threadIdx.x >> 6;   // 0..3
    const int p     = pbase + lane;
    const bool pin  = (p < P);

    // Load 64 channels x 64 pillars, coalesced along P.
#pragma unroll
    for (int r = 0; r < 16; ++r) {
        int c = (r << 2) + row4;
        tile[c][lane] = pin ? pf[(size_t)c * P + p] : 0.0f;
    }

    // Fold in build_map: first 64 threads handle this block's pillars.
    if (threadIdx.x < 64 && pin) {
        int z = coords[3 * p + 0];
        int y = coords[3 * p + 1];
        int x = coords[3 * p + 2];
        map[z + y * NX_G + x] = p;
    }
    __syncthreads();

    // Write pfT rows: thread t -> pillar j = t>>2, channels (t&3)*16 .. +15.
    const int j  = threadIdx.x >> 2;
    const int c0 = (threadIdx.x & 3) << 4;
    if (pbase + j < P) {
        float* dst = pfT + (size_t)(pbase + j) * 64 + c0;
#pragma unroll
        for (int k = 0; k < 16; k += 4) {
            f32x4 v = { tile[c0 + k][j], tile[c0 + k + 1][j],
                        tile[c0 + k + 2][j], tile[c0 + k + 3][j] };
            *reinterpret_cast<f32x4*>(dst + k) = v;
        }
    }
}

__global__ __launch_bounds__(256)
void pp_gather(const float* __restrict__ pfT,
               const int* __restrict__ map,
               float* __restrict__ out) {
    // Block swizzle: i = a + 8*g + 128*b  (a = XCD, g = channel group,
    // qblock = a + 8*b). All 16 g-blocks of a quad-range -> same XCD,
    // dispatched within 128 blocks of each other.
    const int i = blockIdx.x;
    const int a = i & 7;
    const int g = (i >> 3) & 15;
    const int b = i >> 7;
    const int qblock = a + (b << 3);          // [0, 1024)

    const int q  = (qblock << 8) + threadIdx.x;  // quad-cell id, coalesced
    const int c0 = g << 2;

    const int4 pid = reinterpret_cast<const int4*>(map)[q];

    f32x4 va = {0,0,0,0}, vb = {0,0,0,0}, vc = {0,0,0,0}, vd = {0,0,0,0};
    if (pid.x >= 0) va = *reinterpret_cast<const f32x4*>(pfT + ((size_t)pid.x << 6) + c0);
    if (pid.y >= 0) vb = *reinterpret_cast<const f32x4*>(pfT + ((size_t)pid.y << 6) + c0);
    if (pid.z >= 0) vc = *reinterpret_cast<const f32x4*>(pfT + ((size_t)pid.z << 6) + c0);
    if (pid.w >= 0) vd = *reinterpret_cast<const f32x4*>(pfT + ((size_t)pid.w << 6) + c0);

    // 4x4 in-register transpose: channel c0+i gets {va[i], vb[i], vc[i], vd[i]}.
#pragma unroll
    for (int k = 0; k < 4; ++k) {
        f32x4 v = { va[k], vb[k], vc[k], vd[k] };
        f32x4* dst = reinterpret_cast<f32x4*>(out + (size_t)(c0 + k) * NCELLS) + q;
        __builtin_nontemporal_store(v, dst);
    }
}

extern "C" void kernel_launch(void* const* d_in, const int* in_sizes, int n_in,
                              void* d_out, int out_size, void* d_ws, size_t ws_size,
                              hipStream_t stream) {
    const float* pf     = (const float*)d_in[0];
    const int*   coords = (const int*)d_in[1];
    float*       out    = (float*)d_out;
    int*         map    = (int*)d_ws;                       // 4 MiB
    float*       pfT    = (float*)((char*)d_ws + (size_t)NCELLS * sizeof(int)); // 25.6 MB

    const int P = in_sizes[0] / C_CH;  // 100000

    pp_fill_map<<<QUADS / 256, 256, 0, stream>>>((int4*)map);

    const int tblocks = (P + 63) / 64;  // 1563
    pp_transpose_buildmap<<<tblocks, 256, 0, stream>>>(pf, coords, pfT, map, P);

    const int nblocks = GROUPS * QUADS / 256;  // 16384
    pp_gather<<<nblocks, 256, 0, stream>>>(pfT, map, out);
}

// Round 9
// 74.887 us; speedup vs baseline: 1.2009x; 1.0453x over previous
//
#include <hip/hip_runtime.h>
#include <hip/hip_bf16.h>

// PointPillarScatter: out[1, C, NY, NX] (fp32), zero except
// out[c, y, x] = pillar_features[c, p] for pillar p at (z=0, y, x).
// C=64, NX=NY=1024, P=100000.
//   d_in[0]: pillar_features float32 [C, P]
//   d_in[1]: coords int32 [1, P, 3] (z, y, x)
//
// Inverse-map + pf transpose [P,64] + full-coverage gather, NT float4
// stores (round 7: regular stores thrash L2, 89.9; round 8: XCD swizzle
// breaks store locality, 78.3). Round 9 single change vs round-6 best:
// QPT=2 — each thread gathers TWO quads, issuing all 8 predicated random
// loads before any store, to double in-flight reads per wave (the ~32% of
// waves that hit occupied cells stall on pfT load latency otherwise).

constexpr int C_CH   = 64;
constexpr int NX_G   = 1024;
constexpr int NY_G   = 1024;
constexpr int NCELLS = NX_G * NY_G;
constexpr int QUADS  = NCELLS / 4;      // 262144 = 2^18
constexpr int GROUPS = 16;              // channel groups of 4
constexpr int QPT    = 2;               // quads per thread

typedef __attribute__((ext_vector_type(4))) float f32x4;

__global__ void pp_fill_map(int4* __restrict__ map) {
    int t = blockIdx.x * blockDim.x + threadIdx.x;
    map[t] = make_int4(-1, -1, -1, -1);
}

// Transpose pf [64, P] -> pfT [P, 64]; also build the cell->pillar map.
__global__ __launch_bounds__(256)
void pp_transpose_buildmap(const float* __restrict__ pf,
                           const int* __restrict__ coords,
                           float* __restrict__ pfT,
                           int* __restrict__ map, int P) {
    __shared__ float tile[64][65];   // +1 pad
    const int pbase = blockIdx.x * 64;
    const int lane  = threadIdx.x & 63;
    const int row4  = threadIdx.x >> 6;   // 0..3
    const int p     = pbase + lane;
    const bool pin  = (p < P);

#pragma unroll
    for (int r = 0; r < 16; ++r) {
        int c = (r << 2) + row4;
        tile[c][lane] = pin ? pf[(size_t)c * P + p] : 0.0f;
    }

    if (threadIdx.x < 64 && pin) {
        int z = coords[3 * p + 0];
        int y = coords[3 * p + 1];
        int x = coords[3 * p + 2];
        map[z + y * NX_G + x] = p;
    }
    __syncthreads();

    const int j  = threadIdx.x >> 2;
    const int c0 = (threadIdx.x & 3) << 4;
    if (pbase + j < P) {
        float* dst = pfT + (size_t)(pbase + j) * 64 + c0;
#pragma unroll
        for (int k = 0; k < 16; k += 4) {
            f32x4 v = { tile[c0 + k][j], tile[c0 + k + 1][j],
                        tile[c0 + k + 2][j], tile[c0 + k + 3][j] };
            *reinterpret_cast<f32x4*>(dst + k) = v;
        }
    }
}

__global__ __launch_bounds__(256)
void pp_gather(const float* __restrict__ pfT,
               const int* __restrict__ map,
               float* __restrict__ out) {
    // Grid: 8192 blocks. Block i: channel group g = i >> 9,
    // quad range [qb*512, qb*512+512) with qb = i & 511.
    // Thread t handles q_a = qb*512 + t and q_b = q_a + 256.
    const int g  = blockIdx.x >> 9;
    const int qb = blockIdx.x & 511;
    const int qa = (qb << 9) + threadIdx.x;
    const int c0 = g << 2;

    const int4 pidA = reinterpret_cast<const int4*>(map)[qa];
    const int4 pidB = reinterpret_cast<const int4*>(map)[qa + 256];

    // Phase 1: issue ALL predicated random loads (8 independent float4s).
    f32x4 a0 = {0,0,0,0}, a1 = {0,0,0,0}, a2 = {0,0,0,0}, a3 = {0,0,0,0};
    f32x4 b0 = {0,0,0,0}, b1 = {0,0,0,0}, b2 = {0,0,0,0}, b3 = {0,0,0,0};
    if (pidA.x >= 0) a0 = *reinterpret_cast<const f32x4*>(pfT + ((size_t)pidA.x << 6) + c0);
    if (pidA.y >= 0) a1 = *reinterpret_cast<const f32x4*>(pfT + ((size_t)pidA.y << 6) + c0);
    if (pidA.z >= 0) a2 = *reinterpret_cast<const f32x4*>(pfT + ((size_t)pidA.z << 6) + c0);
    if (pidA.w >= 0) a3 = *reinterpret_cast<const f32x4*>(pfT + ((size_t)pidA.w << 6) + c0);
    if (pidB.x >= 0) b0 = *reinterpret_cast<const f32x4*>(pfT + ((size_t)pidB.x << 6) + c0);
    if (pidB.y >= 0) b1 = *reinterpret_cast<const f32x4*>(pfT + ((size_t)pidB.y << 6) + c0);
    if (pidB.z >= 0) b2 = *reinterpret_cast<const f32x4*>(pfT + ((size_t)pidB.z << 6) + c0);
    if (pidB.w >= 0) b3 = *reinterpret_cast<const f32x4*>(pfT + ((size_t)pidB.w << 6) + c0);

    // Phase 2: 4x4 transposes + coalesced NT stores (quad A then quad B).
#pragma unroll
    for (int k = 0; k < 4; ++k) {
        f32x4 v = { a0[k], a1[k], a2[k], a3[k] };
        f32x4* dst = reinterpret_cast<f32x4*>(out + (size_t)(c0 + k) * NCELLS) + qa;
        __builtin_nontemporal_store(v, dst);
    }
#pragma unroll
    for (int k = 0; k < 4; ++k) {
        f32x4 v = { b0[k], b1[k], b2[k], b3[k] };
        f32x4* dst = reinterpret_cast<f32x4*>(out + (size_t)(c0 + k) * NCELLS) + qa + 256;
        __builtin_nontemporal_store(v, dst);
    }
}

extern "C" void kernel_launch(void* const* d_in, const int* in_sizes, int n_in,
                              void* d_out, int out_size, void* d_ws, size_t ws_size,
                              hipStream_t stream) {
    const float* pf     = (const float*)d_in[0];
    const int*   coords = (const int*)d_in[1];
    float*       out    = (float*)d_out;
    int*         map    = (int*)d_ws;                       // 4 MiB
    float*       pfT    = (float*)((char*)d_ws + (size_t)NCELLS * sizeof(int)); // 25.6 MB

    const int P = in_sizes[0] / C_CH;  // 100000

    pp_fill_map<<<QUADS / 256, 256, 0, stream>>>((int4*)map);

    const int tblocks = (P + 63) / 64;  // 1563
    pp_transpose_buildmap<<<tblocks, 256, 0, stream>>>(pf, coords, pfT, map, P);

    const int nblocks = GROUPS * QUADS / (256 * QPT);  // 8192
    pp_gather<<<nblocks, 256, 0, stream>>>(pfT, map, out);
}

// Round 10
// 72.320 us; speedup vs baseline: 1.2435x; 1.0355x over previous
//
#include <hip/hip_runtime.h>
#include <hip/hip_bf16.h>

// PointPillarScatter: out[1, C, NY, NX] (fp32), zero except
// out[c, y, x] = pillar_features[c, p] for pillar p at (z=0, y, x).
// C=64, NX=NY=1024, P=100000.
//   d_in[0]: pillar_features float32 [C, P]
//   d_in[1]: coords int32 [1, P, 3] (z, y, x)
//
// BEST CONFIG (round 6, 72.4 us — restored):
//   inverse map (cell->pillar) + pf transpose to [P, 64] + full-coverage
//   gather writing every output element exactly once via coalesced
//   nontemporal float4 stores; one predicated float4 random load per cell
//   per 4-channel group.
// Measured neighborhood (all worse): CPT=8 87.5 | regular stores 89.9 |
//   XCD swizzle 78.3 | QPT=2 74.9. NT stores essential (L2 kept for
//   map/pfT); CPT=4 with 4.2M threads is the TLP sweet spot.

constexpr int C_CH   = 64;
constexpr int NX_G   = 1024;
constexpr int NY_G   = 1024;
constexpr int NCELLS = NX_G * NY_G;
constexpr int QUADS  = NCELLS / 4;      // 262144 = 2^18
constexpr int GROUPS = 16;              // channel groups of 4

typedef __attribute__((ext_vector_type(4))) float f32x4;

__global__ void pp_fill_map(int4* __restrict__ map) {
    int t = blockIdx.x * blockDim.x + threadIdx.x;
    map[t] = make_int4(-1, -1, -1, -1);
}

// Transpose pf [64, P] -> pfT [P, 64]; also build the cell->pillar map.
__global__ __launch_bounds__(256)
void pp_transpose_buildmap(const float* __restrict__ pf,
                           const int* __restrict__ coords,
                           float* __restrict__ pfT,
                           int* __restrict__ map, int P) {
    __shared__ float tile[64][65];   // +1 pad
    const int pbase = blockIdx.x * 64;
    const int lane  = threadIdx.x & 63;
    const int row4  = threadIdx.x >> 6;   // 0..3
    const int p     = pbase + lane;
    const bool pin  = (p < P);

    // Load 64 channels x 64 pillars, coalesced along P.
#pragma unroll
    for (int r = 0; r < 16; ++r) {
        int c = (r << 2) + row4;
        tile[c][lane] = pin ? pf[(size_t)c * P + p] : 0.0f;
    }

    // Fold in build_map: first 64 threads handle this block's pillars.
    if (threadIdx.x < 64 && pin) {
        int z = coords[3 * p + 0];
        int y = coords[3 * p + 1];
        int x = coords[3 * p + 2];
        map[z + y * NX_G + x] = p;
    }
    __syncthreads();

    // Write pfT rows: thread t -> pillar j = t>>2, channels (t&3)*16 .. +15.
    const int j  = threadIdx.x >> 2;
    const int c0 = (threadIdx.x & 3) << 4;
    if (pbase + j < P) {
        float* dst = pfT + (size_t)(pbase + j) * 64 + c0;
#pragma unroll
        for (int k = 0; k < 16; k += 4) {
            f32x4 v = { tile[c0 + k][j], tile[c0 + k + 1][j],
                        tile[c0 + k + 2][j], tile[c0 + k + 3][j] };
            *reinterpret_cast<f32x4*>(dst + k) = v;
        }
    }
}

__global__ __launch_bounds__(256)
void pp_gather(const float* __restrict__ pfT,
               const int* __restrict__ map,
               float* __restrict__ out) {
    int t = blockIdx.x * blockDim.x + threadIdx.x;  // [0, GROUPS*QUADS)
    int q = t & (QUADS - 1);    // quad-cell id -> coalesced map load + store
    int g = t >> 18;            // channel group (0..15)
    const int4 pid = reinterpret_cast<const int4*>(map)[q];
    const int c0 = g << 2;

    f32x4 a = {0,0,0,0}, b = {0,0,0,0}, c = {0,0,0,0}, d = {0,0,0,0};
    if (pid.x >= 0) a = *reinterpret_cast<const f32x4*>(pfT + ((size_t)pid.x << 6) + c0);
    if (pid.y >= 0) b = *reinterpret_cast<const f32x4*>(pfT + ((size_t)pid.y << 6) + c0);
    if (pid.z >= 0) c = *reinterpret_cast<const f32x4*>(pfT + ((size_t)pid.z << 6) + c0);
    if (pid.w >= 0) d = *reinterpret_cast<const f32x4*>(pfT + ((size_t)pid.w << 6) + c0);

    // 4x4 in-register transpose: channel c0+i gets {a[i], b[i], c[i], d[i]}.
#pragma unroll
    for (int i = 0; i < 4; ++i) {
        f32x4 v = { a[i], b[i], c[i], d[i] };
        f32x4* dst = reinterpret_cast<f32x4*>(out + (size_t)(c0 + i) * NCELLS) + q;
        __builtin_nontemporal_store(v, dst);
    }
}

extern "C" void kernel_launch(void* const* d_in, const int* in_sizes, int n_in,
                              void* d_out, int out_size, void* d_ws, size_t ws_size,
                              hipStream_t stream) {
    const float* pf     = (const float*)d_in[0];
    const int*   coords = (const int*)d_in[1];
    float*       out    = (float*)d_out;
    int*         map    = (int*)d_ws;                       // 4 MiB
    float*       pfT    = (float*)((char*)d_ws + (size_t)NCELLS * sizeof(int)); // 25.6 MB

    const int P = in_sizes[0] / C_CH;  // 100000

    pp_fill_map<<<QUADS / 256, 256, 0, stream>>>((int4*)map);

    const int tblocks = (P + 63) / 64;  // 1563
    pp_transpose_buildmap<<<tblocks, 256, 0, stream>>>(pf, coords, pfT, map, P);

    const int threads = GROUPS * QUADS;  // 4,194,304
    pp_gather<<<threads / 256, 256, 0, stream>>>(pfT, map, out);
}